// Round 6
// baseline (2339.379 us; speedup 1.0000x reference)
//
#include <hip/hip_runtime.h>
#include <hip/hip_bf16.h>
#include <type_traits>

// Problem constants
#define B_  2
#define S_  2048
#define D_  2048
#define H_  16
#define HD_ 128
#define SCALE_ 0.08838834764831845f   // 1/sqrt(128)

using bf16 = __hip_bfloat16;
typedef __attribute__((ext_vector_type(8))) short short8;
typedef __attribute__((ext_vector_type(4))) short short4v;
typedef __attribute__((ext_vector_type(4))) float floatx4;

static __device__ __forceinline__ short bf16_bits(float f) {
    bf16 h = __float2bfloat16(f);
    short s;
    __builtin_memcpy(&s, &h, 2);
    return s;
}

// ---------------------------------------------------------------------------
// GEMM: C[M,N] = A[M,K] @ W[N,K]^T  (nn.Linear). W is ALWAYS fp32 (harness
// input). A is fp32 (x) or bf16 (ws intermediate); C is bf16 (ws) or fp32
// (d_out). fp32 operands are converted to bf16 during LDS staging; MFMA bf16,
// fp32 accumulate. 128x128 tile, BK=32, 4 waves x (64x64 via 4x4 MFMAs).
// Verified gfx950 fragment mappings (m89/m91 lineage):
//   A-frag: lane holds A[m=lane&15][k=(lane>>4)*8+j]
//   B-frag: lane holds B[k=(lane>>4)*8+j][n=lane&15] == W rows for B^T GEMM
//   C/D:    col=lane&15, row=(lane>>4)*4+reg
// ---------------------------------------------------------------------------
template <typename AT, typename CT>
__global__ __launch_bounds__(256) void gemm_bt(const AT* __restrict__ A,
                                               const float* __restrict__ W,
                                               CT* __restrict__ C,
                                               int M, int N, int K) {
    const int n0 = blockIdx.x * 128;
    const int m0 = blockIdx.y * 128;
    const int tid  = threadIdx.x;
    const int wave = tid >> 6;
    const int lane = tid & 63;
    const int wm = wave >> 1, wn = wave & 1;
    const int l16 = lane & 15, quad = lane >> 4;

    __shared__ __align__(16) bf16 As[128][40];   // pad 32->40
    __shared__ __align__(16) bf16 Bs[128][40];

    floatx4 acc[4][4];
    #pragma unroll
    for (int i = 0; i < 4; i++)
        #pragma unroll
        for (int j = 0; j < 4; j++)
            acc[i][j] = (floatx4){0.f, 0.f, 0.f, 0.f};

    for (int kt = 0; kt < K; kt += 32) {
        // Stage A tile 128x32 -> bf16 LDS
        if constexpr (std::is_same_v<AT, float>) {
            #pragma unroll
            for (int i = 0; i < 4; i++) {
                int idx = i * 256 + tid;      // 0..1023
                int row = idx >> 3;           // 0..127
                int ck  = idx & 7;            // 0..7 (4 floats each)
                float4 f = *reinterpret_cast<const float4*>(
                    &A[(size_t)(m0 + row) * K + kt + ck * 4]);
                short4v sv = {bf16_bits(f.x), bf16_bits(f.y),
                              bf16_bits(f.z), bf16_bits(f.w)};
                *reinterpret_cast<short4v*>(&As[row][ck * 4]) = sv;
            }
        } else {
            #pragma unroll
            for (int i = 0; i < 2; i++) {
                int idx = i * 256 + tid;      // 0..511
                int row = idx >> 2;           // 0..127
                int ck  = idx & 3;            // 0..3 (8 bf16 each)
                *reinterpret_cast<int4*>(&As[row][ck * 8]) =
                    *reinterpret_cast<const int4*>(
                        &A[(size_t)(m0 + row) * K + kt + ck * 8]);
            }
        }
        // Stage W tile 128x32 (fp32) -> bf16 LDS
        #pragma unroll
        for (int i = 0; i < 4; i++) {
            int idx = i * 256 + tid;
            int row = idx >> 3;
            int ck  = idx & 7;
            float4 f = *reinterpret_cast<const float4*>(
                &W[(size_t)(n0 + row) * K + kt + ck * 4]);
            short4v sv = {bf16_bits(f.x), bf16_bits(f.y),
                          bf16_bits(f.z), bf16_bits(f.w)};
            *reinterpret_cast<short4v*>(&Bs[row][ck * 4]) = sv;
        }
        __syncthreads();

        short8 af[4], bfrag[4];
        #pragma unroll
        for (int m = 0; m < 4; m++)
            af[m] = *reinterpret_cast<const short8*>(&As[wm * 64 + m * 16 + l16][quad * 8]);
        #pragma unroll
        for (int n = 0; n < 4; n++)
            bfrag[n] = *reinterpret_cast<const short8*>(&Bs[wn * 64 + n * 16 + l16][quad * 8]);

        #pragma unroll
        for (int m = 0; m < 4; m++)
            #pragma unroll
            for (int n = 0; n < 4; n++)
                acc[m][n] = __builtin_amdgcn_mfma_f32_16x16x32_bf16(af[m], bfrag[n], acc[m][n], 0, 0, 0);
        __syncthreads();
    }

    #pragma unroll
    for (int m = 0; m < 4; m++) {
        #pragma unroll
        for (int n = 0; n < 4; n++) {
            #pragma unroll
            for (int r = 0; r < 4; r++) {
                int row = m0 + wm * 64 + m * 16 + quad * 4 + r;
                int col = n0 + wn * 64 + n * 16 + l16;
                if constexpr (std::is_same_v<CT, float>)
                    C[(size_t)row * N + col] = acc[m][n][r];
                else
                    C[(size_t)row * N + col] = __float2bfloat16(acc[m][n][r]);
            }
        }
    }
}

// ---------------------------------------------------------------------------
// RoPE in-place on q,k (bf16 ws buffers, [B,S,H,HD] layout); cos/sin fp32.
// ---------------------------------------------------------------------------
__global__ __launch_bounds__(256) void rope_kernel(bf16* __restrict__ q,
                                                   bf16* __restrict__ k,
                                                   const float* __restrict__ cosT,
                                                   const float* __restrict__ sinT) {
    int idx = blockIdx.x * blockDim.x + threadIdx.x;
    int d = idx & 63;
    int h = (idx >> 6) & 15;
    int s = (idx >> 10) & 2047;
    int rest = idx >> 21;
    int b = rest & 1;
    bf16* p = (rest >> 1) ? k : q;
    size_t base = ((size_t)(b * S_ + s)) * D_ + h * HD_;
    float v0 = __bfloat162float(p[base + d]);
    float v1 = __bfloat162float(p[base + d + 64]);
    float c0 = cosT[s * HD_ + d];
    float s0 = sinT[s * HD_ + d];
    float c1 = cosT[s * HD_ + d + 64];
    float s1 = sinT[s * HD_ + d + 64];
    p[base + d]      = __float2bfloat16(v0 * c0 - v1 * s0);
    p[base + d + 64] = __float2bfloat16(v1 * c1 + v0 * s1);
}

// ---------------------------------------------------------------------------
// Flash attention (causal), q/k/v/o bf16 ws buffers in [B,S,H,HD] layout.
//  - QK^T via MFMA, scores scrubbed (diagnostic tripwire, value-neutral).
//  - PV via VALU from LDS (P fp32 C/D order, V untransposed), V scrubbed.
//  - o MAY ALIAS q (no __restrict__): each block reads its own 64 q-rows x
//    its head's 128 cols into registers before writing exactly those.
// ---------------------------------------------------------------------------
__global__ __launch_bounds__(256) void attn_kernel(const bf16* q,
                                                   const bf16* k,
                                                   const bf16* v,
                                                   bf16* o) {
    const int bx = blockIdx.x;
    const int qt = bx & 31;          // q-tile (S/64 = 32)
    const int h  = (bx >> 5) & 15;
    const int b  = bx >> 9;
    const int q0 = qt * 64;
    const int tid  = threadIdx.x;
    const int wave = tid >> 6;
    const int lane = tid & 63;
    const int l16 = lane & 15, quad = lane >> 4;

    __shared__ __align__(16) bf16  Ks[32][136];
    __shared__ __align__(16) bf16  Vs[32][136];
    __shared__ float Ps[64][33];
    __shared__ float Al[64];
    __shared__ float Linv[64];

    const size_t head_off = (size_t)b * S_ * D_ + (size_t)h * HD_;
    const bf16* qh = q + head_off;
    const bf16* kh = k + head_off;
    const bf16* vh = v + head_off;

    // Q fragments (A layout): row = q0 + wave*16 + l16, k-chunks of 32
    short8 qf[4];
    {
        const bf16* qrow = qh + (size_t)(q0 + wave * 16 + l16) * D_;
        #pragma unroll
        for (int dstep = 0; dstep < 4; dstep++)
            qf[dstep] = *reinterpret_cast<const short8*>(qrow + dstep * 32 + quad * 8);
    }

    // PV role: thread (wave=pw, lane=prow) accumulates O[prow][pw*32..pw*32+31]
    const int prow = tid & 63;
    const int pw   = tid >> 6;
    float ov[32];
    #pragma unroll
    for (int j = 0; j < 32; j++) ov[j] = 0.f;

    float mrow[4], lrow[4];
    #pragma unroll
    for (int r = 0; r < 4; r++) { mrow[r] = -1e30f; lrow[r] = 0.f; }

    const int nkt = qt * 2 + 2;   // causal: k-tiles with k0 <= q0+63
    for (int kt = 0; kt < nkt; kt++) {
        const int k0 = kt * 32;
        #pragma unroll
        for (int i = 0; i < 2; i++) {
            int idx = i * 256 + tid;
            int row = idx >> 4;   // 0..31
            int ck  = idx & 15;   // 0..15
            *reinterpret_cast<int4*>(&Ks[row][ck * 8]) =
                *reinterpret_cast<const int4*>(kh + (size_t)(k0 + row) * D_ + ck * 8);
            *reinterpret_cast<int4*>(&Vs[row][ck * 8]) =
                *reinterpret_cast<const int4*>(vh + (size_t)(k0 + row) * D_ + ck * 8);
        }
        __syncthreads();

        // S = Q K^T : 16 q-rows x 32 k-cols per wave
        floatx4 sc[2];
        sc[0] = (floatx4){0.f, 0.f, 0.f, 0.f};
        sc[1] = (floatx4){0.f, 0.f, 0.f, 0.f};
        #pragma unroll
        for (int nb = 0; nb < 2; nb++) {
            #pragma unroll
            for (int dstep = 0; dstep < 4; dstep++) {
                short8 kf = *reinterpret_cast<const short8*>(&Ks[nb * 16 + l16][dstep * 32 + quad * 8]);
                sc[nb] = __builtin_amdgcn_mfma_f32_16x16x32_bf16(qf[dstep], kf, sc[nb], 0, 0, 0);
            }
        }

        // Online softmax per C/D row (scrub keeps any non-finite score inert)
        const bool need_mask = (k0 + 31 > q0);
        #pragma unroll
        for (int r = 0; r < 4; r++) {
            float rawa = sc[0][r], rawb = sc[1][r];
            float s0 = (fabsf(rawa) < 1e30f) ? rawa * SCALE_ : -1e30f;
            float s1 = (fabsf(rawb) < 1e30f) ? rawb * SCALE_ : -1e30f;
            int qg = q0 + wave * 16 + quad * 4 + r;
            if (need_mask) {
                if (k0 + l16 > qg)      s0 = -1e30f;
                if (k0 + 16 + l16 > qg) s1 = -1e30f;
            }
            float mx = fmaxf(s0, s1);
            #pragma unroll
            for (int off = 1; off < 16; off <<= 1)
                mx = fmaxf(mx, __shfl_xor(mx, off, 16));
            float mnew  = fmaxf(mrow[r], mx);
            float alpha = __expf(mrow[r] - mnew);
            float p0 = __expf(s0 - mnew);
            float p1 = __expf(s1 - mnew);
            float rs = p0 + p1;
            #pragma unroll
            for (int off = 1; off < 16; off <<= 1)
                rs += __shfl_xor(rs, off, 16);
            lrow[r] = lrow[r] * alpha + rs;
            mrow[r] = mnew;
            int prow_w = wave * 16 + quad * 4 + r;
            Ps[prow_w][l16]      = p0;
            Ps[prow_w][16 + l16] = p1;
            if (l16 == 0) Al[prow_w] = alpha;
        }
        __syncthreads();   // Ps/Al visible to PV role

        // PV via VALU with V scrub: ov = ov*alpha + sum_key P*V
        {
            float alpha2 = Al[prow];
            #pragma unroll
            for (int j = 0; j < 32; j++) ov[j] *= alpha2;
            for (int key = 0; key < 32; key++) {
                float p = Ps[prow][key];
                const unsigned int* vrow =
                    reinterpret_cast<const unsigned int*>(&Vs[key][pw * 32]);
                #pragma unroll
                for (int jj = 0; jj < 16; jj++) {
                    unsigned int pk = vrow[jj];
                    float v0 = __uint_as_float(pk << 16);
                    float v1 = __uint_as_float(pk & 0xFFFF0000u);
                    v0 = (fabsf(v0) < 1e4f) ? v0 : 0.f;   // diagnostic scrub
                    v1 = (fabsf(v1) < 1e4f) ? v1 : 0.f;
                    ov[2 * jj]     += p * v0;
                    ov[2 * jj + 1] += p * v1;
                }
            }
        }
        __syncthreads();   // before next tile overwrites Ks/Vs/Ps
    }

    // Publish 1/l from score role, consume in PV role
    #pragma unroll
    for (int r = 0; r < 4; r++)
        if (l16 == 0) Linv[wave * 16 + quad * 4 + r] = 1.f / lrow[r];
    __syncthreads();

    float linv = Linv[prow];
    bf16* orow = o + head_off + (size_t)(q0 + prow) * D_ + pw * 32;
    #pragma unroll
    for (int jj = 0; jj < 16; jj++) {
        __hip_bfloat162 pr;
        pr.x = __float2bfloat16(ov[2 * jj] * linv);
        pr.y = __float2bfloat16(ov[2 * jj + 1] * linv);
        *reinterpret_cast<__hip_bfloat162*>(orow + 2 * jj) = pr;
    }
}

// ---------------------------------------------------------------------------
// I/O dtypes per the reference: ALL inputs fp32, output fp32 (the five-round
// NaN was fp32 buffers read as bf16 -> random-exponent garbage incl. NaN).
// Workspace (bf16 intermediates, 50.3 MB total):
//   qb/kb/vb = ws[0/1/2 * 16.7MB); attention out aliases qb.
// ---------------------------------------------------------------------------
extern "C" void kernel_launch(void* const* d_in, const int* in_sizes, int n_in,
                              void* d_out, int out_size, void* d_ws, size_t ws_size,
                              hipStream_t stream) {
    const float* x    = (const float*)d_in[0];
    // d_in[1] = mask: causal -1e9 additive mask; handled exactly by causal skip.
    const float* cosT = (const float*)d_in[2];
    const float* sinT = (const float*)d_in[3];
    const float* Wq   = (const float*)d_in[4];
    const float* Wk   = (const float*)d_in[5];
    const float* Wv   = (const float*)d_in[6];
    const float* Wo   = (const float*)d_in[7];
    float* out = (float*)d_out;

    const size_t tsz = (size_t)B_ * S_ * D_;   // 8,388,608 elements
    bf16* qb = (bf16*)d_ws;
    bf16* kb = qb + tsz;
    bf16* vb = kb + tsz;
    bf16* ab = qb;                 // attention out aliases Q (no restrict in attn)

    dim3 ggrid(D_ / 128, (B_ * S_) / 128);     // 16 x 32
    gemm_bt<float, bf16><<<ggrid, 256, 0, stream>>>(x, Wq, qb, B_ * S_, D_, D_);
    gemm_bt<float, bf16><<<ggrid, 256, 0, stream>>>(x, Wk, kb, B_ * S_, D_, D_);
    gemm_bt<float, bf16><<<ggrid, 256, 0, stream>>>(x, Wv, vb, B_ * S_, D_, D_);

    rope_kernel<<<(2 * B_ * S_ * H_ * 64) / 256, 256, 0, stream>>>(qb, kb, cosT, sinT);

    attn_kernel<<<B_ * H_ * (S_ / 64), 256, 0, stream>>>(qb, kb, vb, ab);

    gemm_bt<bf16, float><<<ggrid, 256, 0, stream>>>(ab, Wo, out, B_ * S_, D_, D_);
}

// Round 7
// 737.579 us; speedup vs baseline: 3.1717x; 3.1717x over previous
//
#include <hip/hip_runtime.h>
#include <hip/hip_bf16.h>
#include <type_traits>

// Problem constants
#define B_  2
#define S_  2048
#define D_  2048
#define H_  16
#define HD_ 128
#define SCALE_ 0.08838834764831845f   // 1/sqrt(128)

using bf16 = __hip_bfloat16;
typedef __attribute__((ext_vector_type(8))) short short8;
typedef __attribute__((ext_vector_type(4))) short short4v;
typedef __attribute__((ext_vector_type(4))) float floatx4;

static __device__ __forceinline__ short bf16_bits(float f) {
    bf16 h = __float2bfloat16(f);
    short s;
    __builtin_memcpy(&s, &h, 2);
    return s;
}

// ---------------------------------------------------------------------------
// GEMM: C[M,N] = A[M,K] @ W[N,K]^T  (nn.Linear). W fp32; A fp32 (x) or bf16
// (ws); C bf16 (ws) or fp32 (d_out). fp32 -> bf16 conversion during LDS
// staging; MFMA bf16, fp32 accumulate. 128x128 tile, BK=32, 4 waves.
// ---------------------------------------------------------------------------
template <typename AT, typename CT>
__global__ __launch_bounds__(256) void gemm_bt(const AT* __restrict__ A,
                                               const float* __restrict__ W,
                                               CT* __restrict__ C,
                                               int M, int N, int K) {
    const int n0 = blockIdx.x * 128;
    const int m0 = blockIdx.y * 128;
    const int tid  = threadIdx.x;
    const int wave = tid >> 6;
    const int lane = tid & 63;
    const int wm = wave >> 1, wn = wave & 1;
    const int l16 = lane & 15, quad = lane >> 4;

    __shared__ __align__(16) bf16 As[128][40];
    __shared__ __align__(16) bf16 Bs[128][40];

    floatx4 acc[4][4];
    #pragma unroll
    for (int i = 0; i < 4; i++)
        #pragma unroll
        for (int j = 0; j < 4; j++)
            acc[i][j] = (floatx4){0.f, 0.f, 0.f, 0.f};

    for (int kt = 0; kt < K; kt += 32) {
        if constexpr (std::is_same_v<AT, float>) {
            #pragma unroll
            for (int i = 0; i < 4; i++) {
                int idx = i * 256 + tid;
                int row = idx >> 3;
                int ck  = idx & 7;
                float4 f = *reinterpret_cast<const float4*>(
                    &A[(size_t)(m0 + row) * K + kt + ck * 4]);
                short4v sv = {bf16_bits(f.x), bf16_bits(f.y),
                              bf16_bits(f.z), bf16_bits(f.w)};
                *reinterpret_cast<short4v*>(&As[row][ck * 4]) = sv;
            }
        } else {
            #pragma unroll
            for (int i = 0; i < 2; i++) {
                int idx = i * 256 + tid;
                int row = idx >> 2;
                int ck  = idx & 3;
                *reinterpret_cast<int4*>(&As[row][ck * 8]) =
                    *reinterpret_cast<const int4*>(
                        &A[(size_t)(m0 + row) * K + kt + ck * 8]);
            }
        }
        #pragma unroll
        for (int i = 0; i < 4; i++) {
            int idx = i * 256 + tid;
            int row = idx >> 3;
            int ck  = idx & 7;
            float4 f = *reinterpret_cast<const float4*>(
                &W[(size_t)(n0 + row) * K + kt + ck * 4]);
            short4v sv = {bf16_bits(f.x), bf16_bits(f.y),
                          bf16_bits(f.z), bf16_bits(f.w)};
            *reinterpret_cast<short4v*>(&Bs[row][ck * 4]) = sv;
        }
        __syncthreads();

        short8 af[4], bfrag[4];
        #pragma unroll
        for (int m = 0; m < 4; m++)
            af[m] = *reinterpret_cast<const short8*>(&As[wm * 64 + m * 16 + l16][quad * 8]);
        #pragma unroll
        for (int n = 0; n < 4; n++)
            bfrag[n] = *reinterpret_cast<const short8*>(&Bs[wn * 64 + n * 16 + l16][quad * 8]);

        #pragma unroll
        for (int m = 0; m < 4; m++)
            #pragma unroll
            for (int n = 0; n < 4; n++)
                acc[m][n] = __builtin_amdgcn_mfma_f32_16x16x32_bf16(af[m], bfrag[n], acc[m][n], 0, 0, 0);
        __syncthreads();
    }

    #pragma unroll
    for (int m = 0; m < 4; m++) {
        #pragma unroll
        for (int n = 0; n < 4; n++) {
            #pragma unroll
            for (int r = 0; r < 4; r++) {
                int row = m0 + wm * 64 + m * 16 + quad * 4 + r;
                int col = n0 + wn * 64 + n * 16 + l16;
                if constexpr (std::is_same_v<CT, float>)
                    C[(size_t)row * N + col] = acc[m][n][r];
                else
                    C[(size_t)row * N + col] = __float2bfloat16(acc[m][n][r]);
            }
        }
    }
}

// ---------------------------------------------------------------------------
// RoPE in-place on q,k (bf16 ws, [B,S,H,HD]); cos/sin fp32.
// ---------------------------------------------------------------------------
__global__ __launch_bounds__(256) void rope_kernel(bf16* __restrict__ q,
                                                   bf16* __restrict__ k,
                                                   const float* __restrict__ cosT,
                                                   const float* __restrict__ sinT) {
    int idx = blockIdx.x * blockDim.x + threadIdx.x;
    int d = idx & 63;
    int h = (idx >> 6) & 15;
    int s = (idx >> 10) & 2047;
    int rest = idx >> 21;
    int b = rest & 1;
    bf16* p = (rest >> 1) ? k : q;
    size_t base = ((size_t)(b * S_ + s)) * D_ + h * HD_;
    float v0 = __bfloat162float(p[base + d]);
    float v1 = __bfloat162float(p[base + d + 64]);
    float c0 = cosT[s * HD_ + d];
    float s0 = sinT[s * HD_ + d];
    float c1 = cosT[s * HD_ + d + 64];
    float s1 = sinT[s * HD_ + d + 64];
    p[base + d]      = __float2bfloat16(v0 * c0 - v1 * s0);
    p[base + d + 64] = __float2bfloat16(v1 * c1 + v0 * s1);
}

// ---------------------------------------------------------------------------
// Flash attention (causal), MFMA for BOTH QK^T and PV (R7).
//  - K staged [32][136] vector b128 (as before, verified).
//  - V staged TRANSPOSED via column-writer: thread t owns d=(t&127),
//    keys 16*(t>>7)..+15; 16 coalesced scalar global loads, then 16
//    contiguous shorts into Vt[d][.] (row stride 36 shorts = 18 words,
//    gcd(18,32)=2 -> ~2-way bank conflicts ~ free). Fixes R1's 16-way
//    scatter; enables contiguous PV B-frag reads.
//  - P: C/D layout -> per-wave Pl[16][40] (bf16 bits) -> barrier -> A-frag
//    b128 reload (m120-verified transform pattern).
//  - Causal skip: nkt = 2*qt+2 tiles; qt reversed so big blocks launch first.
//  - o aliases q safely (no __restrict__): block reads its own 64 rows x
//    head cols into registers before writing exactly those.
// ---------------------------------------------------------------------------
__global__ __launch_bounds__(256) void attn_kernel(const bf16* q,
                                                   const bf16* k,
                                                   const bf16* v,
                                                   bf16* o) {
    const int bx = blockIdx.x;
    const int qt = 31 - (bx & 31);   // reversed: heaviest q-tiles first
    const int h  = (bx >> 5) & 15;
    const int b  = bx >> 9;
    const int q0 = qt * 64;
    const int tid  = threadIdx.x;
    const int wave = tid >> 6;
    const int lane = tid & 63;
    const int l16 = lane & 15, quad = lane >> 4;

    __shared__ __align__(16) bf16  Ks[32][136];
    __shared__ __align__(16) short Vt[128][36];   // V^T: Vt[d][key], pad 32->36
    __shared__ __align__(16) short Pl[4][16][40]; // per-wave P (bf16 bits)

    const size_t head_off = (size_t)b * S_ * D_ + (size_t)h * HD_;
    const bf16* qh = q + head_off;
    const bf16* kh = k + head_off;
    const short* vh = reinterpret_cast<const short*>(v) + head_off;

    // Q fragments (A layout): row = q0 + wave*16 + l16, k-chunks of 32
    short8 qf[4];
    {
        const bf16* qrow = qh + (size_t)(q0 + wave * 16 + l16) * D_;
        #pragma unroll
        for (int dstep = 0; dstep < 4; dstep++)
            qf[dstep] = *reinterpret_cast<const short8*>(qrow + dstep * 32 + quad * 8);
    }

    floatx4 ov[8];
    #pragma unroll
    for (int i = 0; i < 8; i++) ov[i] = (floatx4){0.f, 0.f, 0.f, 0.f};
    float mrow[4], lrow[4];
    #pragma unroll
    for (int r = 0; r < 4; r++) { mrow[r] = -1e30f; lrow[r] = 0.f; }

    // Vt column-writer identity
    const int vd  = tid & 127;    // d column owned by this thread
    const int vkh = tid >> 7;     // key half: rows 16*vkh .. 16*vkh+15

    const int nkt = qt * 2 + 2;   // causal: k-tiles with k0 <= q0+63
    for (int kt = 0; kt < nkt; kt++) {
        const int k0 = kt * 32;
        // Stage K tile [32][128] (vector b128)
        #pragma unroll
        for (int i = 0; i < 2; i++) {
            int idx = i * 256 + tid;
            int row = idx >> 4;
            int ck  = idx & 15;
            *reinterpret_cast<int4*>(&Ks[row][ck * 8]) =
                *reinterpret_cast<const int4*>(kh + (size_t)(k0 + row) * D_ + ck * 8);
        }
        // Stage V transposed: 16 coalesced scalar loads, contiguous LDS write
        {
            const short* vcol = vh + (size_t)(k0 + vkh * 16) * D_ + vd;
            short tmp[16];
            #pragma unroll
            for (int r = 0; r < 16; r++)
                tmp[r] = vcol[(size_t)r * D_];
            #pragma unroll
            for (int c = 0; c < 4; c++) {
                short4v sv = {tmp[c*4], tmp[c*4+1], tmp[c*4+2], tmp[c*4+3]};
                *reinterpret_cast<short4v*>(&Vt[vd][vkh * 16 + c * 4]) = sv;
            }
        }
        __syncthreads();

        // S = Q K^T : 16 q-rows x 32 k-cols per wave (2 n-blocks)
        floatx4 sc[2];
        sc[0] = (floatx4){0.f, 0.f, 0.f, 0.f};
        sc[1] = (floatx4){0.f, 0.f, 0.f, 0.f};
        #pragma unroll
        for (int nb = 0; nb < 2; nb++) {
            #pragma unroll
            for (int dstep = 0; dstep < 4; dstep++) {
                short8 kf = *reinterpret_cast<const short8*>(&Ks[nb * 16 + l16][dstep * 32 + quad * 8]);
                sc[nb] = __builtin_amdgcn_mfma_f32_16x16x32_bf16(qf[dstep], kf, sc[nb], 0, 0, 0);
            }
        }

        // Online softmax per C/D row (rows in quad's 16 lanes, shfl width 16)
        const bool need_mask = (k0 + 31 > q0);
        #pragma unroll
        for (int r = 0; r < 4; r++) {
            float s0 = sc[0][r] * SCALE_;
            float s1 = sc[1][r] * SCALE_;
            if (need_mask) {
                int qg = q0 + wave * 16 + quad * 4 + r;
                if (k0 + l16 > qg)      s0 = -1e30f;
                if (k0 + 16 + l16 > qg) s1 = -1e30f;
            }
            float mx = fmaxf(s0, s1);
            #pragma unroll
            for (int off = 1; off < 16; off <<= 1)
                mx = fmaxf(mx, __shfl_xor(mx, off, 16));
            float mnew  = fmaxf(mrow[r], mx);
            float alpha = __expf(mrow[r] - mnew);
            float p0 = __expf(s0 - mnew);
            float p1 = __expf(s1 - mnew);
            float rs = p0 + p1;
            #pragma unroll
            for (int off = 1; off < 16; off <<= 1)
                rs += __shfl_xor(rs, off, 16);
            lrow[r] = lrow[r] * alpha + rs;
            mrow[r] = mnew;
            Pl[wave][quad * 4 + r][l16]      = bf16_bits(p0);
            Pl[wave][quad * 4 + r][16 + l16] = bf16_bits(p1);
            #pragma unroll
            for (int db = 0; db < 8; db++) ov[db][r] *= alpha;
        }
        __syncthreads();   // fence Pl store->reload (and all-waves alignment)

        // PV: P a-frag (A layout) x Vt b-frags, K=32 in one MFMA per d-block
        short8 pf = *reinterpret_cast<const short8*>(&Pl[wave][l16][quad * 8]);
        #pragma unroll
        for (int db = 0; db < 8; db++) {
            const short* vp = &Vt[db * 16 + l16][quad * 8];
            short4v a = *reinterpret_cast<const short4v*>(vp);
            short4v c = *reinterpret_cast<const short4v*>(vp + 4);
            short8 vf = {a[0], a[1], a[2], a[3], c[0], c[1], c[2], c[3]};
            ov[db] = __builtin_amdgcn_mfma_f32_16x16x32_bf16(pf, vf, ov[db], 0, 0, 0);
        }
        __syncthreads();   // before next tile overwrites Ks/Vt
    }

    // Epilogue: normalize and store (C/D layout rows)
    bf16* oh = o + head_off;
    #pragma unroll
    for (int r = 0; r < 4; r++) {
        float inv = 1.f / lrow[r];
        int srow = q0 + wave * 16 + quad * 4 + r;
        #pragma unroll
        for (int db = 0; db < 8; db++)
            oh[(size_t)srow * D_ + db * 16 + l16] = __float2bfloat16(ov[db][r] * inv);
    }
}

// ---------------------------------------------------------------------------
// I/O: ALL inputs fp32, output fp32 (confirmed R6). bf16 ws intermediates.
// ---------------------------------------------------------------------------
extern "C" void kernel_launch(void* const* d_in, const int* in_sizes, int n_in,
                              void* d_out, int out_size, void* d_ws, size_t ws_size,
                              hipStream_t stream) {
    const float* x    = (const float*)d_in[0];
    // d_in[1] = mask: causal -1e9 additive mask; handled exactly by causal skip.
    const float* cosT = (const float*)d_in[2];
    const float* sinT = (const float*)d_in[3];
    const float* Wq   = (const float*)d_in[4];
    const float* Wk   = (const float*)d_in[5];
    const float* Wv   = (const float*)d_in[6];
    const float* Wo   = (const float*)d_in[7];
    float* out = (float*)d_out;

    const size_t tsz = (size_t)B_ * S_ * D_;
    bf16* qb = (bf16*)d_ws;
    bf16* kb = qb + tsz;
    bf16* vb = kb + tsz;
    bf16* ab = qb;                 // attention out aliases Q (no restrict in attn)

    dim3 ggrid(D_ / 128, (B_ * S_) / 128);     // 16 x 32
    gemm_bt<float, bf16><<<ggrid, 256, 0, stream>>>(x, Wq, qb, B_ * S_, D_, D_);
    gemm_bt<float, bf16><<<ggrid, 256, 0, stream>>>(x, Wk, kb, B_ * S_, D_, D_);
    gemm_bt<float, bf16><<<ggrid, 256, 0, stream>>>(x, Wv, vb, B_ * S_, D_, D_);

    rope_kernel<<<(2 * B_ * S_ * H_ * 64) / 256, 256, 0, stream>>>(qb, kb, cosT, sinT);

    attn_kernel<<<B_ * H_ * (S_ / 64), 256, 0, stream>>>(qb, kb, vb, ab);

    gemm_bt<bf16, float><<<ggrid, 256, 0, stream>>>(ab, Wo, out, B_ * S_, D_, D_);
}

// Round 8
// 569.723 us; speedup vs baseline: 4.1062x; 1.2946x over previous
//
#include <hip/hip_runtime.h>
#include <hip/hip_bf16.h>
#include <type_traits>

// Problem constants
#define B_  2
#define S_  2048
#define D_  2048
#define H_  16
#define HD_ 128
#define SCALE_ 0.08838834764831845f   // 1/sqrt(128)

using bf16 = __hip_bfloat16;
typedef __attribute__((ext_vector_type(8))) short short8;
typedef __attribute__((ext_vector_type(4))) short short4v;
typedef __attribute__((ext_vector_type(4))) float floatx4;

static __device__ __forceinline__ short bf16_bits(float f) {
    bf16 h = __float2bfloat16(f);
    short s;
    __builtin_memcpy(&s, &h, 2);
    return s;
}

// async global->LDS, 16B per lane; LDS dest is wave-uniform base + lane*16
static __device__ __forceinline__ void load_lds16(const bf16* gp, bf16* lp) {
    __builtin_amdgcn_global_load_lds(
        (const __attribute__((address_space(1))) void*)gp,
        (__attribute__((address_space(3))) void*)lp, 16, 0, 0);
}

// ---------------------------------------------------------------------------
// Convert kernel: 6 chunks of 2^22 fp32 elements -> bf16.
// chunks: 0,1 = x (2^23 elems); 2..5 = Wq,Wk,Wv,Wo (2^22 each).
// ---------------------------------------------------------------------------
__global__ __launch_bounds__(256) void conv_kernel(
        const float* s0, const float* s1, const float* s2,
        const float* s3, const float* s4, const float* s5,
        bf16* d0, bf16* d1, bf16* d2, bf16* d3, bf16* d4, bf16* d5) {
    int cid = blockIdx.x >> 12;                     // 4096 blocks per chunk
    int off = ((blockIdx.x & 4095) * 256 + threadIdx.x) * 4;
    const float* s; bf16* d;
    switch (cid) {
        case 0: s = s0; d = d0; break;
        case 1: s = s1; d = d1; break;
        case 2: s = s2; d = d2; break;
        case 3: s = s3; d = d3; break;
        case 4: s = s4; d = d4; break;
        default: s = s5; d = d5; break;
    }
    float4 f = *reinterpret_cast<const float4*>(s + off);
    short4v sv = {bf16_bits(f.x), bf16_bits(f.y), bf16_bits(f.z), bf16_bits(f.w)};
    *reinterpret_cast<short4v*>(d + off) = sv;
}

// ---------------------------------------------------------------------------
// m97-style GEMM core: C[M,N] = A[M,K] @ W[N,K]^T, A/W bf16, fp32 acc.
// 128x128 tile, BK=32, global_load_lds width-16 staging into UNPADDED LDS
// (lane-contiguous layout is required by global_load_lds), b128 frag reads.
// ---------------------------------------------------------------------------
template <typename CT>
static __device__ __forceinline__ void gemm_core(const bf16* A, const bf16* W,
                                                 CT* C, int M, int N, int K,
                                                 int m0, int n0) {
    const int tid  = threadIdx.x;
    const int wave = tid >> 6;
    const int lane = tid & 63;
    const int wm = wave >> 1, wn = wave & 1;
    const int l16 = lane & 15, quad = lane >> 4;

    __shared__ __align__(16) bf16 As[128 * 32];   // unpadded, 8 KB
    __shared__ __align__(16) bf16 Bs[128 * 32];

    floatx4 acc[4][4];
    #pragma unroll
    for (int i = 0; i < 4; i++)
        #pragma unroll
        for (int j = 0; j < 4; j++)
            acc[i][j] = (floatx4){0.f, 0.f, 0.f, 0.f};

    const int srow = (lane >> 2);        // 0..15 within segment
    const int scol = (lane & 3) * 8;     // 0/8/16/24

    for (int kt = 0; kt < K; kt += 32) {
        #pragma unroll
        for (int i = 0; i < 2; i++) {
            int seg  = wave * 2 + i;             // 0..7, 16 rows each
            int row  = seg * 16 + srow;
            load_lds16(&A[(size_t)(m0 + row) * K + kt + scol], &As[seg * 512]);
            load_lds16(&W[(size_t)(n0 + row) * K + kt + scol], &Bs[seg * 512]);
        }
        __syncthreads();   // drains vmcnt (global_load_lds) + lgkm

        short8 af[4], bfrag[4];
        #pragma unroll
        for (int m = 0; m < 4; m++)
            af[m] = *reinterpret_cast<const short8*>(&As[(wm * 64 + m * 16 + l16) * 32 + quad * 8]);
        #pragma unroll
        for (int n = 0; n < 4; n++)
            bfrag[n] = *reinterpret_cast<const short8*>(&Bs[(wn * 64 + n * 16 + l16) * 32 + quad * 8]);

        #pragma unroll
        for (int m = 0; m < 4; m++)
            #pragma unroll
            for (int n = 0; n < 4; n++)
                acc[m][n] = __builtin_amdgcn_mfma_f32_16x16x32_bf16(af[m], bfrag[n], acc[m][n], 0, 0, 0);
        __syncthreads();
    }

    #pragma unroll
    for (int m = 0; m < 4; m++) {
        #pragma unroll
        for (int n = 0; n < 4; n++) {
            #pragma unroll
            for (int r = 0; r < 4; r++) {
                int row = m0 + wm * 64 + m * 16 + quad * 4 + r;
                int col = n0 + wn * 64 + n * 16 + l16;
                if constexpr (std::is_same_v<CT, float>)
                    C[(size_t)row * N + col] = acc[m][n][r];
                else
                    C[(size_t)row * N + col] = __float2bfloat16(acc[m][n][r]);
            }
        }
    }
}

// Fused QKV projection: grid (48, 32); blockIdx.x>>4 selects Q/K/V.
__global__ __launch_bounds__(256) void gemm_qkv(const bf16* __restrict__ X,
                                                const bf16* __restrict__ Wq,
                                                const bf16* __restrict__ Wk,
                                                const bf16* __restrict__ Wv,
                                                bf16* __restrict__ Q,
                                                bf16* __restrict__ Kb,
                                                bf16* __restrict__ V) {
    int wi = blockIdx.x >> 4;
    int n0 = (blockIdx.x & 15) * 128;
    int m0 = blockIdx.y * 128;
    const bf16* W = (wi == 0) ? Wq : (wi == 1) ? Wk : Wv;
    bf16* C = (wi == 0) ? Q : (wi == 1) ? Kb : V;
    gemm_core<bf16>(X, W, C, B_ * S_, D_, D_, m0, n0);
}

// O projection: bf16 x bf16 -> fp32 out.
__global__ __launch_bounds__(256) void gemm_o(const bf16* __restrict__ A,
                                              const bf16* __restrict__ W,
                                              float* __restrict__ C) {
    gemm_core<float>(A, W, C, B_ * S_, D_, D_, blockIdx.y * 128, blockIdx.x * 128);
}

// ---------------------------------------------------------------------------
// Fallback GEMM (R7, proven): inline fp32->bf16 convert staging.
// ---------------------------------------------------------------------------
template <typename AT, typename CT>
__global__ __launch_bounds__(256) void gemm_bt(const AT* __restrict__ A,
                                               const float* __restrict__ W,
                                               CT* __restrict__ C,
                                               int M, int N, int K) {
    const int n0 = blockIdx.x * 128;
    const int m0 = blockIdx.y * 128;
    const int tid  = threadIdx.x;
    const int wave = tid >> 6;
    const int lane = tid & 63;
    const int wm = wave >> 1, wn = wave & 1;
    const int l16 = lane & 15, quad = lane >> 4;

    __shared__ __align__(16) bf16 As[128][40];
    __shared__ __align__(16) bf16 Bs[128][40];

    floatx4 acc[4][4];
    #pragma unroll
    for (int i = 0; i < 4; i++)
        #pragma unroll
        for (int j = 0; j < 4; j++)
            acc[i][j] = (floatx4){0.f, 0.f, 0.f, 0.f};

    for (int kt = 0; kt < K; kt += 32) {
        if constexpr (std::is_same_v<AT, float>) {
            #pragma unroll
            for (int i = 0; i < 4; i++) {
                int idx = i * 256 + tid;
                int row = idx >> 3;
                int ck  = idx & 7;
                float4 f = *reinterpret_cast<const float4*>(
                    &A[(size_t)(m0 + row) * K + kt + ck * 4]);
                short4v sv = {bf16_bits(f.x), bf16_bits(f.y),
                              bf16_bits(f.z), bf16_bits(f.w)};
                *reinterpret_cast<short4v*>(&As[row][ck * 4]) = sv;
            }
        } else {
            #pragma unroll
            for (int i = 0; i < 2; i++) {
                int idx = i * 256 + tid;
                int row = idx >> 2;
                int ck  = idx & 3;
                *reinterpret_cast<int4*>(&As[row][ck * 8]) =
                    *reinterpret_cast<const int4*>(
                        &A[(size_t)(m0 + row) * K + kt + ck * 8]);
            }
        }
        #pragma unroll
        for (int i = 0; i < 4; i++) {
            int idx = i * 256 + tid;
            int row = idx >> 3;
            int ck  = idx & 7;
            float4 f = *reinterpret_cast<const float4*>(
                &W[(size_t)(n0 + row) * K + kt + ck * 4]);
            short4v sv = {bf16_bits(f.x), bf16_bits(f.y),
                          bf16_bits(f.z), bf16_bits(f.w)};
            *reinterpret_cast<short4v*>(&Bs[row][ck * 4]) = sv;
        }
        __syncthreads();

        short8 af[4], bfrag[4];
        #pragma unroll
        for (int m = 0; m < 4; m++)
            af[m] = *reinterpret_cast<const short8*>(&As[wm * 64 + m * 16 + l16][quad * 8]);
        #pragma unroll
        for (int n = 0; n < 4; n++)
            bfrag[n] = *reinterpret_cast<const short8*>(&Bs[wn * 64 + n * 16 + l16][quad * 8]);

        #pragma unroll
        for (int m = 0; m < 4; m++)
            #pragma unroll
            for (int n = 0; n < 4; n++)
                acc[m][n] = __builtin_amdgcn_mfma_f32_16x16x32_bf16(af[m], bfrag[n], acc[m][n], 0, 0, 0);
        __syncthreads();
    }

    #pragma unroll
    for (int m = 0; m < 4; m++) {
        #pragma unroll
        for (int n = 0; n < 4; n++) {
            #pragma unroll
            for (int r = 0; r < 4; r++) {
                int row = m0 + wm * 64 + m * 16 + quad * 4 + r;
                int col = n0 + wn * 64 + n * 16 + l16;
                if constexpr (std::is_same_v<CT, float>)
                    C[(size_t)row * N + col] = acc[m][n][r];
                else
                    C[(size_t)row * N + col] = __float2bfloat16(acc[m][n][r]);
            }
        }
    }
}

// ---------------------------------------------------------------------------
// RoPE in-place on q,k (bf16 ws, [B,S,H,HD]); cos/sin fp32.
// ---------------------------------------------------------------------------
__global__ __launch_bounds__(256) void rope_kernel(bf16* __restrict__ q,
                                                   bf16* __restrict__ k,
                                                   const float* __restrict__ cosT,
                                                   const float* __restrict__ sinT) {
    int idx = blockIdx.x * blockDim.x + threadIdx.x;
    int d = idx & 63;
    int h = (idx >> 6) & 15;
    int s = (idx >> 10) & 2047;
    int rest = idx >> 21;
    int b = rest & 1;
    bf16* p = (rest >> 1) ? k : q;
    size_t base = ((size_t)(b * S_ + s)) * D_ + h * HD_;
    float v0 = __bfloat162float(p[base + d]);
    float v1 = __bfloat162float(p[base + d + 64]);
    float c0 = cosT[s * HD_ + d];
    float s0 = sinT[s * HD_ + d];
    float c1 = cosT[s * HD_ + d + 64];
    float s1 = sinT[s * HD_ + d + 64];
    p[base + d]      = __float2bfloat16(v0 * c0 - v1 * s0);
    p[base + d + 64] = __float2bfloat16(v1 * c1 + v0 * s1);
}

// ---------------------------------------------------------------------------
// Flash attention (causal), MFMA QK^T + MFMA PV (R7, verified).
// ---------------------------------------------------------------------------
__global__ __launch_bounds__(256) void attn_kernel(const bf16* q,
                                                   const bf16* k,
                                                   const bf16* v,
                                                   bf16* o) {
    const int bx = blockIdx.x;
    const int qt = 31 - (bx & 31);   // reversed: heaviest q-tiles first
    const int h  = (bx >> 5) & 15;
    const int b  = bx >> 9;
    const int q0 = qt * 64;
    const int tid  = threadIdx.x;
    const int wave = tid >> 6;
    const int lane = tid & 63;
    const int l16 = lane & 15, quad = lane >> 4;

    __shared__ __align__(16) bf16  Ks[32][136];
    __shared__ __align__(16) short Vt[128][36];   // V^T: Vt[d][key]
    __shared__ __align__(16) short Pl[4][16][40]; // per-wave P (bf16 bits)

    const size_t head_off = (size_t)b * S_ * D_ + (size_t)h * HD_;
    const bf16* qh = q + head_off;
    const bf16* kh = k + head_off;
    const short* vh = reinterpret_cast<const short*>(v) + head_off;

    short8 qf[4];
    {
        const bf16* qrow = qh + (size_t)(q0 + wave * 16 + l16) * D_;
        #pragma unroll
        for (int dstep = 0; dstep < 4; dstep++)
            qf[dstep] = *reinterpret_cast<const short8*>(qrow + dstep * 32 + quad * 8);
    }

    floatx4 ov[8];
    #pragma unroll
    for (int i = 0; i < 8; i++) ov[i] = (floatx4){0.f, 0.f, 0.f, 0.f};
    float mrow[4], lrow[4];
    #pragma unroll
    for (int r = 0; r < 4; r++) { mrow[r] = -1e30f; lrow[r] = 0.f; }

    const int vd  = tid & 127;
    const int vkh = tid >> 7;

    const int nkt = qt * 2 + 2;
    for (int kt = 0; kt < nkt; kt++) {
        const int k0 = kt * 32;
        #pragma unroll
        for (int i = 0; i < 2; i++) {
            int idx = i * 256 + tid;
            int row = idx >> 4;
            int ck  = idx & 15;
            *reinterpret_cast<int4*>(&Ks[row][ck * 8]) =
                *reinterpret_cast<const int4*>(kh + (size_t)(k0 + row) * D_ + ck * 8);
        }
        {
            const short* vcol = vh + (size_t)(k0 + vkh * 16) * D_ + vd;
            short tmp[16];
            #pragma unroll
            for (int r = 0; r < 16; r++)
                tmp[r] = vcol[(size_t)r * D_];
            #pragma unroll
            for (int c = 0; c < 4; c++) {
                short4v sv = {tmp[c*4], tmp[c*4+1], tmp[c*4+2], tmp[c*4+3]};
                *reinterpret_cast<short4v*>(&Vt[vd][vkh * 16 + c * 4]) = sv;
            }
        }
        __syncthreads();

        floatx4 sc[2];
        sc[0] = (floatx4){0.f, 0.f, 0.f, 0.f};
        sc[1] = (floatx4){0.f, 0.f, 0.f, 0.f};
        #pragma unroll
        for (int nb = 0; nb < 2; nb++) {
            #pragma unroll
            for (int dstep = 0; dstep < 4; dstep++) {
                short8 kf = *reinterpret_cast<const short8*>(&Ks[nb * 16 + l16][dstep * 32 + quad * 8]);
                sc[nb] = __builtin_amdgcn_mfma_f32_16x16x32_bf16(qf[dstep], kf, sc[nb], 0, 0, 0);
            }
        }

        const bool need_mask = (k0 + 31 > q0);
        #pragma unroll
        for (int r = 0; r < 4; r++) {
            float s0 = sc[0][r] * SCALE_;
            float s1 = sc[1][r] * SCALE_;
            if (need_mask) {
                int qg = q0 + wave * 16 + quad * 4 + r;
                if (k0 + l16 > qg)      s0 = -1e30f;
                if (k0 + 16 + l16 > qg) s1 = -1e30f;
            }
            float mx = fmaxf(s0, s1);
            #pragma unroll
            for (int off = 1; off < 16; off <<= 1)
                mx = fmaxf(mx, __shfl_xor(mx, off, 16));
            float mnew  = fmaxf(mrow[r], mx);
            float alpha = __expf(mrow[r] - mnew);
            float p0 = __expf(s0 - mnew);
            float p1 = __expf(s1 - mnew);
            float rs = p0 + p1;
            #pragma unroll
            for (int off = 1; off < 16; off <<= 1)
                rs += __shfl_xor(rs, off, 16);
            lrow[r] = lrow[r] * alpha + rs;
            mrow[r] = mnew;
            Pl[wave][quad * 4 + r][l16]      = bf16_bits(p0);
            Pl[wave][quad * 4 + r][16 + l16] = bf16_bits(p1);
            #pragma unroll
            for (int db = 0; db < 8; db++) ov[db][r] *= alpha;
        }
        __syncthreads();

        short8 pf = *reinterpret_cast<const short8*>(&Pl[wave][l16][quad * 8]);
        #pragma unroll
        for (int db = 0; db < 8; db++) {
            const short* vp = &Vt[db * 16 + l16][quad * 8];
            short4v a = *reinterpret_cast<const short4v*>(vp);
            short4v c = *reinterpret_cast<const short4v*>(vp + 4);
            short8 vf = {a[0], a[1], a[2], a[3], c[0], c[1], c[2], c[3]};
            ov[db] = __builtin_amdgcn_mfma_f32_16x16x32_bf16(pf, vf, ov[db], 0, 0, 0);
        }
        __syncthreads();
    }

    bf16* oh = o + head_off;
    #pragma unroll
    for (int r = 0; r < 4; r++) {
        float inv = 1.f / lrow[r];
        int srow = q0 + wave * 16 + quad * 4 + r;
        #pragma unroll
        for (int db = 0; db < 8; db++)
            oh[(size_t)srow * D_ + db * 16 + l16] = __float2bfloat16(ov[db][r] * inv);
    }
}

// ---------------------------------------------------------------------------
// I/O: ALL inputs fp32, output fp32 (confirmed R6). bf16 ws intermediates.
// Fast path (needs 100.7 MB ws): pre-convert x+weights to bf16, fused QKV
// GEMM + O GEMM with global_load_lds staging. Fallback = R7 (50.3 MB).
// ---------------------------------------------------------------------------
extern "C" void kernel_launch(void* const* d_in, const int* in_sizes, int n_in,
                              void* d_out, int out_size, void* d_ws, size_t ws_size,
                              hipStream_t stream) {
    const float* x    = (const float*)d_in[0];
    // d_in[1] = mask: causal -1e9 additive mask; handled exactly by causal skip.
    const float* cosT = (const float*)d_in[2];
    const float* sinT = (const float*)d_in[3];
    const float* Wq   = (const float*)d_in[4];
    const float* Wk   = (const float*)d_in[5];
    const float* Wv   = (const float*)d_in[6];
    const float* Wo   = (const float*)d_in[7];
    float* out = (float*)d_out;

    const size_t tsz = (size_t)B_ * S_ * D_;     // 8,388,608 elements
    const size_t wsz = (size_t)D_ * D_;          // 4,194,304 elements
    bf16* qb = (bf16*)d_ws;
    bf16* kb = qb + tsz;
    bf16* vb = kb + tsz;
    bf16* ab = qb;                               // attn out aliases Q

    const size_t need = (3 * tsz + tsz + 4 * wsz) * sizeof(bf16);  // 100.7 MB

    if (ws_size >= need) {
        bf16* xb  = vb + tsz;
        bf16* wqb = xb + tsz;
        bf16* wkb = wqb + wsz;
        bf16* wvb = wkb + wsz;
        bf16* wob = wvb + wsz;

        // 6 chunks of 2^22 elements: x (2), Wq, Wk, Wv, Wo
        conv_kernel<<<24576, 256, 0, stream>>>(
            x, x + wsz, Wq, Wk, Wv, Wo,
            xb, xb + wsz, wqb, wkb, wvb, wob);

        gemm_qkv<<<dim3(48, 32), 256, 0, stream>>>(xb, wqb, wkb, wvb, qb, kb, vb);

        rope_kernel<<<(2 * B_ * S_ * H_ * 64) / 256, 256, 0, stream>>>(qb, kb, cosT, sinT);

        attn_kernel<<<B_ * H_ * (S_ / 64), 256, 0, stream>>>(qb, kb, vb, ab);

        gemm_o<<<dim3(16, 32), 256, 0, stream>>>(ab, wob, out);
    } else {
        dim3 ggrid(D_ / 128, (B_ * S_) / 128);   // 16 x 32
        gemm_bt<float, bf16><<<ggrid, 256, 0, stream>>>(x, Wq, qb, B_ * S_, D_, D_);
        gemm_bt<float, bf16><<<ggrid, 256, 0, stream>>>(x, Wk, kb, B_ * S_, D_, D_);
        gemm_bt<float, bf16><<<ggrid, 256, 0, stream>>>(x, Wv, vb, B_ * S_, D_, D_);

        rope_kernel<<<(2 * B_ * S_ * H_ * 64) / 256, 256, 0, stream>>>(qb, kb, cosT, sinT);

        attn_kernel<<<B_ * H_ * (S_ / 64), 256, 0, stream>>>(qb, kb, vb, ab);

        gemm_bt<bf16, float><<<ggrid, 256, 0, stream>>>(ab, Wo, out, B_ * S_, D_, D_);
    }
}

// Round 9
// 511.480 us; speedup vs baseline: 4.5737x; 1.1139x over previous
//
#include <hip/hip_runtime.h>
#include <hip/hip_bf16.h>
#include <type_traits>

// Problem constants
#define B_  2
#define S_  2048
#define D_  2048
#define H_  16
#define HD_ 128
#define SCALE_ 0.08838834764831845f   // 1/sqrt(128)

using bf16 = __hip_bfloat16;
typedef __attribute__((ext_vector_type(8))) short short8;
typedef __attribute__((ext_vector_type(4))) short short4v;
typedef __attribute__((ext_vector_type(4))) float floatx4;

static __device__ __forceinline__ short bf16_bits(float f) {
    bf16 h = __float2bfloat16(f);
    short s;
    __builtin_memcpy(&s, &h, 2);
    return s;
}

// async global->LDS, 16B per lane; LDS dest is wave-uniform base + lane*16
static __device__ __forceinline__ void load_lds16(const bf16* gp, bf16* lp) {
    __builtin_amdgcn_global_load_lds(
        (const __attribute__((address_space(1))) void*)gp,
        (__attribute__((address_space(3))) void*)lp, 16, 0, 0);
}

// ---------------------------------------------------------------------------
// Convert kernel: 6 chunks of 2^22 fp32 elements -> bf16.
// ---------------------------------------------------------------------------
__global__ __launch_bounds__(256) void conv_kernel(
        const float* s0, const float* s1, const float* s2,
        const float* s3, const float* s4, const float* s5,
        bf16* d0, bf16* d1, bf16* d2, bf16* d3, bf16* d4, bf16* d5) {
    int cid = blockIdx.x >> 12;                     // 4096 blocks per chunk
    int off = ((blockIdx.x & 4095) * 256 + threadIdx.x) * 4;
    const float* s; bf16* d;
    switch (cid) {
        case 0: s = s0; d = d0; break;
        case 1: s = s1; d = d1; break;
        case 2: s = s2; d = d2; break;
        case 3: s = s3; d = d3; break;
        case 4: s = s4; d = d4; break;
        default: s = s5; d = d5; break;
    }
    float4 f = *reinterpret_cast<const float4*>(s + off);
    short4v sv = {bf16_bits(f.x), bf16_bits(f.y), bf16_bits(f.z), bf16_bits(f.w)};
    *reinterpret_cast<short4v*>(d + off) = sv;
}

// ---------------------------------------------------------------------------
// m97-style GEMM core: 128x128 tile, BK=32, global_load_lds width-16.
// ---------------------------------------------------------------------------
template <typename CT>
static __device__ __forceinline__ void gemm_core(const bf16* A, const bf16* W,
                                                 CT* C, int M, int N, int K,
                                                 int m0, int n0) {
    const int tid  = threadIdx.x;
    const int wave = tid >> 6;
    const int lane = tid & 63;
    const int wm = wave >> 1, wn = wave & 1;
    const int l16 = lane & 15, quad = lane >> 4;

    __shared__ __align__(16) bf16 As[128 * 32];
    __shared__ __align__(16) bf16 Bs[128 * 32];

    floatx4 acc[4][4];
    #pragma unroll
    for (int i = 0; i < 4; i++)
        #pragma unroll
        for (int j = 0; j < 4; j++)
            acc[i][j] = (floatx4){0.f, 0.f, 0.f, 0.f};

    const int srow = (lane >> 2);
    const int scol = (lane & 3) * 8;

    for (int kt = 0; kt < K; kt += 32) {
        #pragma unroll
        for (int i = 0; i < 2; i++) {
            int seg  = wave * 2 + i;
            int row  = seg * 16 + srow;
            load_lds16(&A[(size_t)(m0 + row) * K + kt + scol], &As[seg * 512]);
            load_lds16(&W[(size_t)(n0 + row) * K + kt + scol], &Bs[seg * 512]);
        }
        __syncthreads();

        short8 af[4], bfrag[4];
        #pragma unroll
        for (int m = 0; m < 4; m++)
            af[m] = *reinterpret_cast<const short8*>(&As[(wm * 64 + m * 16 + l16) * 32 + quad * 8]);
        #pragma unroll
        for (int n = 0; n < 4; n++)
            bfrag[n] = *reinterpret_cast<const short8*>(&Bs[(wn * 64 + n * 16 + l16) * 32 + quad * 8]);

        #pragma unroll
        for (int m = 0; m < 4; m++)
            #pragma unroll
            for (int n = 0; n < 4; n++)
                acc[m][n] = __builtin_amdgcn_mfma_f32_16x16x32_bf16(af[m], bfrag[n], acc[m][n], 0, 0, 0);
        __syncthreads();
    }

    #pragma unroll
    for (int m = 0; m < 4; m++) {
        #pragma unroll
        for (int n = 0; n < 4; n++) {
            #pragma unroll
            for (int r = 0; r < 4; r++) {
                int row = m0 + wm * 64 + m * 16 + quad * 4 + r;
                int col = n0 + wn * 64 + n * 16 + l16;
                if constexpr (std::is_same_v<CT, float>)
                    C[(size_t)row * N + col] = acc[m][n][r];
                else
                    C[(size_t)row * N + col] = __float2bfloat16(acc[m][n][r]);
            }
        }
    }
}

__global__ __launch_bounds__(256) void gemm_qkv(const bf16* __restrict__ X,
                                                const bf16* __restrict__ Wq,
                                                const bf16* __restrict__ Wk,
                                                const bf16* __restrict__ Wv,
                                                bf16* __restrict__ Q,
                                                bf16* __restrict__ Kb,
                                                bf16* __restrict__ V) {
    int wi = blockIdx.x >> 4;
    int n0 = (blockIdx.x & 15) * 128;
    int m0 = blockIdx.y * 128;
    const bf16* W = (wi == 0) ? Wq : (wi == 1) ? Wk : Wv;
    bf16* C = (wi == 0) ? Q : (wi == 1) ? Kb : V;
    gemm_core<bf16>(X, W, C, B_ * S_, D_, D_, m0, n0);
}

__global__ __launch_bounds__(256) void gemm_o(const bf16* __restrict__ A,
                                              const bf16* __restrict__ W,
                                              float* __restrict__ C) {
    gemm_core<float>(A, W, C, B_ * S_, D_, D_, blockIdx.y * 128, blockIdx.x * 128);
}

// ---------------------------------------------------------------------------
// Fallback GEMM (R7, proven): inline fp32->bf16 convert staging.
// ---------------------------------------------------------------------------
template <typename AT, typename CT>
__global__ __launch_bounds__(256) void gemm_bt(const AT* __restrict__ A,
                                               const float* __restrict__ W,
                                               CT* __restrict__ C,
                                               int M, int N, int K) {
    const int n0 = blockIdx.x * 128;
    const int m0 = blockIdx.y * 128;
    const int tid  = threadIdx.x;
    const int wave = tid >> 6;
    const int lane = tid & 63;
    const int wm = wave >> 1, wn = wave & 1;
    const int l16 = lane & 15, quad = lane >> 4;

    __shared__ __align__(16) bf16 As[128][40];
    __shared__ __align__(16) bf16 Bs[128][40];

    floatx4 acc[4][4];
    #pragma unroll
    for (int i = 0; i < 4; i++)
        #pragma unroll
        for (int j = 0; j < 4; j++)
            acc[i][j] = (floatx4){0.f, 0.f, 0.f, 0.f};

    for (int kt = 0; kt < K; kt += 32) {
        if constexpr (std::is_same_v<AT, float>) {
            #pragma unroll
            for (int i = 0; i < 4; i++) {
                int idx = i * 256 + tid;
                int row = idx >> 3;
                int ck  = idx & 7;
                float4 f = *reinterpret_cast<const float4*>(
                    &A[(size_t)(m0 + row) * K + kt + ck * 4]);
                short4v sv = {bf16_bits(f.x), bf16_bits(f.y),
                              bf16_bits(f.z), bf16_bits(f.w)};
                *reinterpret_cast<short4v*>(&As[row][ck * 4]) = sv;
            }
        } else {
            #pragma unroll
            for (int i = 0; i < 2; i++) {
                int idx = i * 256 + tid;
                int row = idx >> 2;
                int ck  = idx & 3;
                *reinterpret_cast<int4*>(&As[row][ck * 8]) =
                    *reinterpret_cast<const int4*>(
                        &A[(size_t)(m0 + row) * K + kt + ck * 8]);
            }
        }
        #pragma unroll
        for (int i = 0; i < 4; i++) {
            int idx = i * 256 + tid;
            int row = idx >> 3;
            int ck  = idx & 7;
            float4 f = *reinterpret_cast<const float4*>(
                &W[(size_t)(n0 + row) * K + kt + ck * 4]);
            short4v sv = {bf16_bits(f.x), bf16_bits(f.y),
                          bf16_bits(f.z), bf16_bits(f.w)};
            *reinterpret_cast<short4v*>(&Bs[row][ck * 4]) = sv;
        }
        __syncthreads();

        short8 af[4], bfrag[4];
        #pragma unroll
        for (int m = 0; m < 4; m++)
            af[m] = *reinterpret_cast<const short8*>(&As[wm * 64 + m * 16 + l16][quad * 8]);
        #pragma unroll
        for (int n = 0; n < 4; n++)
            bfrag[n] = *reinterpret_cast<const short8*>(&Bs[wn * 64 + n * 16 + l16][quad * 8]);

        #pragma unroll
        for (int m = 0; m < 4; m++)
            #pragma unroll
            for (int n = 0; n < 4; n++)
                acc[m][n] = __builtin_amdgcn_mfma_f32_16x16x32_bf16(af[m], bfrag[n], acc[m][n], 0, 0, 0);
        __syncthreads();
    }

    #pragma unroll
    for (int m = 0; m < 4; m++) {
        #pragma unroll
        for (int n = 0; n < 4; n++) {
            #pragma unroll
            for (int r = 0; r < 4; r++) {
                int row = m0 + wm * 64 + m * 16 + quad * 4 + r;
                int col = n0 + wn * 64 + n * 16 + l16;
                if constexpr (std::is_same_v<CT, float>)
                    C[(size_t)row * N + col] = acc[m][n][r];
                else
                    C[(size_t)row * N + col] = __float2bfloat16(acc[m][n][r]);
            }
        }
    }
}

// ---------------------------------------------------------------------------
// RoPE in-place on q,k (bf16 ws, [B,S,H,HD]); cos/sin fp32.
// Q is PRE-SCALED by 1/sqrt(HD) here (attention uses raw MFMA scores).
// ---------------------------------------------------------------------------
__global__ __launch_bounds__(256) void rope_kernel(bf16* __restrict__ q,
                                                   bf16* __restrict__ k,
                                                   const float* __restrict__ cosT,
                                                   const float* __restrict__ sinT) {
    int idx = blockIdx.x * blockDim.x + threadIdx.x;
    int d = idx & 63;
    int h = (idx >> 6) & 15;
    int s = (idx >> 10) & 2047;
    int rest = idx >> 21;
    int b = rest & 1;
    bool isq = !(rest >> 1);
    bf16* p = isq ? q : k;
    float sc = isq ? SCALE_ : 1.0f;
    size_t base = ((size_t)(b * S_ + s)) * D_ + h * HD_;
    float v0 = __bfloat162float(p[base + d]);
    float v1 = __bfloat162float(p[base + d + 64]);
    float c0 = cosT[s * HD_ + d];
    float s0 = sinT[s * HD_ + d];
    float c1 = cosT[s * HD_ + d + 64];
    float s1 = sinT[s * HD_ + d + 64];
    p[base + d]      = __float2bfloat16((v0 * c0 - v1 * s0) * sc);
    p[base + d + 64] = __float2bfloat16((v1 * c1 + v0 * s1) * sc);
}

// ---------------------------------------------------------------------------
// Flash attention (causal) R9: 128-row Q-tiles (wave owns 32 rows = 2
// m-blocks), 32-key K/V tiles, MFMA QK^T + MFMA PV.
//  - l accumulated via ones-column MFMA (no sum-shfl): l = l*alpha + P.1
//  - Pl is wave-private: in-wave s_waitcnt lgkmcnt(0) fence instead of a
//    block barrier -> 2 barriers/tile.
//  - Q pre-scaled by 1/sqrt(HD) in rope_kernel.
//  - o aliases q safely: block reads its 128 rows x head cols to registers
//    before writing exactly those.
// ---------------------------------------------------------------------------
__global__ __launch_bounds__(256) void attn_kernel(const bf16* q,
                                                   const bf16* k,
                                                   const bf16* v,
                                                   bf16* o) {
    const int bx = blockIdx.x;
    const int qt = 15 - (bx & 15);   // reversed: heaviest q-tiles first
    const int h  = (bx >> 4) & 15;
    const int b  = bx >> 8;
    const int q0 = qt * 128;
    const int tid  = threadIdx.x;
    const int wave = tid >> 6;
    const int lane = tid & 63;
    const int l16 = lane & 15, quad = lane >> 4;

    __shared__ __align__(16) bf16  Ks[32][136];
    __shared__ __align__(16) short Vt[128][36];      // V^T: Vt[d][key]
    __shared__ __align__(16) short Pl[4][2][16][40]; // per-wave P (bf16 bits)

    const size_t head_off = (size_t)b * S_ * D_ + (size_t)h * HD_;
    const bf16* qh = q + head_off;
    const bf16* kh = k + head_off;
    const short* vh = reinterpret_cast<const short*>(v) + head_off;

    // Q fragments: wave owns rows q0 + wave*32 + mb*16 + l16
    short8 qf[2][4];
    #pragma unroll
    for (int mb = 0; mb < 2; mb++) {
        const bf16* qrow = qh + (size_t)(q0 + wave * 32 + mb * 16 + l16) * D_;
        #pragma unroll
        for (int dstep = 0; dstep < 4; dstep++)
            qf[mb][dstep] = *reinterpret_cast<const short8*>(qrow + dstep * 32 + quad * 8);
    }

    floatx4 ov[2][8];
    floatx4 lacc[2];
    #pragma unroll
    for (int mb = 0; mb < 2; mb++) {
        lacc[mb] = (floatx4){0.f, 0.f, 0.f, 0.f};
        #pragma unroll
        for (int i = 0; i < 8; i++) ov[mb][i] = (floatx4){0.f, 0.f, 0.f, 0.f};
    }
    float mrow[2][4];
    #pragma unroll
    for (int mb = 0; mb < 2; mb++)
        #pragma unroll
        for (int r = 0; r < 4; r++) mrow[mb][r] = -1e30f;

    const short ONEB = 0x3F80;   // bf16 1.0
    const short8 ones = {ONEB, ONEB, ONEB, ONEB, ONEB, ONEB, ONEB, ONEB};

    const int vd  = tid & 127;
    const int vkh = tid >> 7;

    const int nkt = qt * 4 + 4;   // causal: k-tiles with k0 <= q0+127
    for (int kt = 0; kt < nkt; kt++) {
        const int k0 = kt * 32;
        // Stage K tile [32][128] (b128)
        #pragma unroll
        for (int i = 0; i < 2; i++) {
            int idx = i * 256 + tid;
            int row = idx >> 4;
            int ck  = idx & 15;
            *reinterpret_cast<int4*>(&Ks[row][ck * 8]) =
                *reinterpret_cast<const int4*>(kh + (size_t)(k0 + row) * D_ + ck * 8);
        }
        // Stage V transposed (column-writer)
        {
            const short* vcol = vh + (size_t)(k0 + vkh * 16) * D_ + vd;
            short tmp[16];
            #pragma unroll
            for (int r = 0; r < 16; r++)
                tmp[r] = vcol[(size_t)r * D_];
            #pragma unroll
            for (int c = 0; c < 4; c++) {
                short4v sv = {tmp[c*4], tmp[c*4+1], tmp[c*4+2], tmp[c*4+3]};
                *reinterpret_cast<short4v*>(&Vt[vd][vkh * 16 + c * 4]) = sv;
            }
        }
        __syncthreads();

        // S = Q K^T : 32 q-rows x 32 k-cols per wave
        floatx4 sc[2][2];
        #pragma unroll
        for (int mb = 0; mb < 2; mb++)
            #pragma unroll
            for (int nb = 0; nb < 2; nb++)
                sc[mb][nb] = (floatx4){0.f, 0.f, 0.f, 0.f};
        #pragma unroll
        for (int dstep = 0; dstep < 4; dstep++) {
            short8 kf0 = *reinterpret_cast<const short8*>(&Ks[l16][dstep * 32 + quad * 8]);
            short8 kf1 = *reinterpret_cast<const short8*>(&Ks[16 + l16][dstep * 32 + quad * 8]);
            #pragma unroll
            for (int mb = 0; mb < 2; mb++) {
                sc[mb][0] = __builtin_amdgcn_mfma_f32_16x16x32_bf16(qf[mb][dstep], kf0, sc[mb][0], 0, 0, 0);
                sc[mb][1] = __builtin_amdgcn_mfma_f32_16x16x32_bf16(qf[mb][dstep], kf1, sc[mb][1], 0, 0, 0);
            }
        }

        // Online softmax (max via shfl; sum via ones-MFMA below)
        #pragma unroll
        for (int mb = 0; mb < 2; mb++) {
            const int qbase = q0 + wave * 32 + mb * 16;
            const bool need_mask = (k0 + 31 > qbase);
            #pragma unroll
            for (int r = 0; r < 4; r++) {
                float s0 = sc[mb][0][r];
                float s1 = sc[mb][1][r];
                if (need_mask) {
                    int qg = qbase + quad * 4 + r;
                    if (k0 + l16 > qg)      s0 = -1e30f;
                    if (k0 + 16 + l16 > qg) s1 = -1e30f;
                }
                float mx = fmaxf(s0, s1);
                #pragma unroll
                for (int off = 1; off < 16; off <<= 1)
                    mx = fmaxf(mx, __shfl_xor(mx, off, 16));
                float mnew  = fmaxf(mrow[mb][r], mx);
                float alpha = __expf(mrow[mb][r] - mnew);
                mrow[mb][r] = mnew;
                Pl[wave][mb][quad * 4 + r][l16]      = bf16_bits(__expf(s0 - mnew));
                Pl[wave][mb][quad * 4 + r][16 + l16] = bf16_bits(__expf(s1 - mnew));
                lacc[mb][r] *= alpha;
                #pragma unroll
                for (int db = 0; db < 8; db++) ov[mb][db][r] *= alpha;
            }
        }

        // In-wave fence: Pl is wave-private; DS pipe is in-order per wave.
        __asm__ volatile("s_waitcnt lgkmcnt(0)" ::: "memory");

        // PV + l-sum via MFMA
        short8 pf0 = *reinterpret_cast<const short8*>(&Pl[wave][0][l16][quad * 8]);
        short8 pf1 = *reinterpret_cast<const short8*>(&Pl[wave][1][l16][quad * 8]);
        #pragma unroll
        for (int db = 0; db < 8; db++) {
            const short* vp = &Vt[db * 16 + l16][quad * 8];
            short4v a = *reinterpret_cast<const short4v*>(vp);
            short4v c = *reinterpret_cast<const short4v*>(vp + 4);
            short8 vf = {a[0], a[1], a[2], a[3], c[0], c[1], c[2], c[3]};
            ov[0][db] = __builtin_amdgcn_mfma_f32_16x16x32_bf16(pf0, vf, ov[0][db], 0, 0, 0);
            ov[1][db] = __builtin_amdgcn_mfma_f32_16x16x32_bf16(pf1, vf, ov[1][db], 0, 0, 0);
        }
        lacc[0] = __builtin_amdgcn_mfma_f32_16x16x32_bf16(pf0, ones, lacc[0], 0, 0, 0);
        lacc[1] = __builtin_amdgcn_mfma_f32_16x16x32_bf16(pf1, ones, lacc[1], 0, 0, 0);
        __syncthreads();
    }

    // Epilogue: normalize and store (C/D layout rows)
    bf16* oh = o + head_off;
    #pragma unroll
    for (int mb = 0; mb < 2; mb++) {
        #pragma unroll
        for (int r = 0; r < 4; r++) {
            float inv = 1.f / lacc[mb][r];
            int srow = q0 + wave * 32 + mb * 16 + quad * 4 + r;
            #pragma unroll
            for (int db = 0; db < 8; db++)
                oh[(size_t)srow * D_ + db * 16 + l16] = __float2bfloat16(ov[mb][db][r] * inv);
        }
    }
}

// ---------------------------------------------------------------------------
// I/O: ALL inputs fp32, output fp32 (confirmed R6). bf16 ws intermediates.
// ---------------------------------------------------------------------------
extern "C" void kernel_launch(void* const* d_in, const int* in_sizes, int n_in,
                              void* d_out, int out_size, void* d_ws, size_t ws_size,
                              hipStream_t stream) {
    const float* x    = (const float*)d_in[0];
    // d_in[1] = mask: causal -1e9 additive mask; handled exactly by causal skip.
    const float* cosT = (const float*)d_in[2];
    const float* sinT = (const float*)d_in[3];
    const float* Wq   = (const float*)d_in[4];
    const float* Wk   = (const float*)d_in[5];
    const float* Wv   = (const float*)d_in[6];
    const float* Wo   = (const float*)d_in[7];
    float* out = (float*)d_out;

    const size_t tsz = (size_t)B_ * S_ * D_;
    const size_t wsz = (size_t)D_ * D_;
    bf16* qb = (bf16*)d_ws;
    bf16* kb = qb + tsz;
    bf16* vb = kb + tsz;
    bf16* ab = qb;                               // attn out aliases Q

    const size_t need = (3 * tsz + tsz + 4 * wsz) * sizeof(bf16);  // 100.7 MB

    if (ws_size >= need) {
        bf16* xb  = vb + tsz;
        bf16* wqb = xb + tsz;
        bf16* wkb = wqb + wsz;
        bf16* wvb = wkb + wsz;
        bf16* wob = wvb + wsz;

        conv_kernel<<<24576, 256, 0, stream>>>(
            x, x + wsz, Wq, Wk, Wv, Wo,
            xb, xb + wsz, wqb, wkb, wvb, wob);

        gemm_qkv<<<dim3(48, 32), 256, 0, stream>>>(xb, wqb, wkb, wvb, qb, kb, vb);

        rope_kernel<<<(2 * B_ * S_ * H_ * 64) / 256, 256, 0, stream>>>(qb, kb, cosT, sinT);

        attn_kernel<<<B_ * H_ * (S_ / 128), 256, 0, stream>>>(qb, kb, vb, ab);

        gemm_o<<<dim3(16, 32), 256, 0, stream>>>(ab, wob, out);
    } else {
        dim3 ggrid(D_ / 128, (B_ * S_) / 128);
        gemm_bt<float, bf16><<<ggrid, 256, 0, stream>>>(x, Wq, qb, B_ * S_, D_, D_);
        gemm_bt<float, bf16><<<ggrid, 256, 0, stream>>>(x, Wk, kb, B_ * S_, D_, D_);
        gemm_bt<float, bf16><<<ggrid, 256, 0, stream>>>(x, Wv, vb, B_ * S_, D_, D_);

        rope_kernel<<<(2 * B_ * S_ * H_ * 64) / 256, 256, 0, stream>>>(qb, kb, cosT, sinT);

        attn_kernel<<<B_ * H_ * (S_ / 128), 256, 0, stream>>>(qb, kb, vb, ab);

        gemm_bt<bf16, float><<<ggrid, 256, 0, stream>>>(ab, Wo, out, B_ * S_, D_, D_);
    }
}